// Round 14
// baseline (344.698 us; speedup 1.0000x reference)
//
#include <hip/hip_runtime.h>

typedef unsigned short ushort_t;
typedef unsigned int uint_t;

typedef __bf16 bf16x8 __attribute__((ext_vector_type(8)));
typedef float f32x4 __attribute__((ext_vector_type(4)));

static __device__ __forceinline__ float bf2f(ushort_t h) {
    return __uint_as_float(((uint_t)h) << 16);
}
static __device__ __forceinline__ ushort_t f2bf(float f) {
    uint_t u = __float_as_uint(f);
    u = u + 0x7FFFu + ((u >> 16) & 1u);
    return (ushort_t)(u >> 16);
}
// pack two floats as bf16 (round-half-up) into one dword: low=lo, high=hi
static __device__ __forceinline__ uint_t pkbf(float lo, float hi) {
    uint_t a = __float_as_uint(lo) + 0x8000u;
    uint_t b = __float_as_uint(hi) + 0x8000u;
    return __builtin_amdgcn_perm(b, a, 0x07060302u);
}

// ---------------- constants ----------------
#define BB 32
#define HH 56
#define WW_ 56
#define CC 128
#define NHEAD 4
#define WS 7
#define SS 3
#define LL (HH * WW_)           // 3136
#define NTOK (BB * LL)          // 100352
#define NWIN (BB * 64)          // 2048
#define NN 49
#define HD 32
#define PLS 40                  // P half LDS stride (shorts) — conflict-free
#define VTS 72                  // Vt LDS stride (shorts) — conflict-free

// windowed token -> global token (shift map)
static __device__ __forceinline__ int win2tok(int wid) {
    int win = wid / NN, t = wid - win * NN;
    int bb = win >> 6, wrem = win & 63;
    int wi = wrem >> 3, wj = wrem & 7;
    int ti = t / WS, tj = t - ti * WS;
    int hh = wi * WS + ti + SS; if (hh >= HH) hh -= HH;
    int ww = wj * WS + tj + SS; if (ww >= WW_) ww -= WW_;
    return bb * LL + hh * WW_ + ww;
}

// ============ merged prep: weights fp32->bf16 (blocks 0..767) +
//              bias table x log2(e) (blocks 768..771) ============
__global__ __launch_bounds__(256) void prep_all(
    const float* __restrict__ qkv_w, const float* __restrict__ proj_w,
    const float* __restrict__ fc1_w, const float* __restrict__ fc2_w,
    ushort_t* __restrict__ dst,
    const float* __restrict__ rpb, const int* __restrict__ rel_idx,
    float* __restrict__ bias) {
    int b = blockIdx.x;
    if (b < 768) {
        int i = b * 256 + threadIdx.x;   // 0 .. 196607
        const float* src;
        int off;
        if (i < 49152)        { src = qkv_w;  off = i; }
        else if (i < 65536)   { src = proj_w; off = i - 49152; }
        else if (i < 131072)  { src = fc1_w;  off = i - 65536; }
        else                  { src = fc2_w;  off = i - 131072; }
        dst[i] = f2bf(src[off]);
    } else {
        int h = b - 768;
        for (int idx = threadIdx.x; idx < 4096; idx += 256) {
            int i = idx >> 6, j = idx & 63;
            float v = 0.f;
            if (i < NN && j < NN)
                v = rpb[(size_t)rel_idx[i * NN + j] * NHEAD + h] * 1.4426950409f;
            bias[h * 4096 + idx] = v;
        }
    }
}

// ============ fully-fused: LN1+QKV+attn+proj+residual+LN2+MLP ============
// r14 = r13 + (a) pkbf pair-packing in LN1/LN2/O-store (96 f2bf -> 48 pkbf,
// ~240 VALU ops/thread saved), (b) LN2's x reload issued BEFORE the proj
// phase (register-destined global loads stay in flight under proj's MFMA;
// proj-phase VGPR ~103+32 stays under the 124 peak set by QKV).
// Base: r10 structure (QK swizzle, Vt in LDS, 3 blocks/CU) + r13 exp2.
__global__ __launch_bounds__(256) void swin_fused(
    const float* __restrict__ x, const float* __restrict__ g1,
    const float* __restrict__ b1ln, const ushort_t* __restrict__ wq,
    const float* __restrict__ qkv_b, const float* __restrict__ bias,
    const ushort_t* __restrict__ wp, const float* __restrict__ proj_b,
    const float* __restrict__ g2, const float* __restrict__ b2,
    const ushort_t* __restrict__ w1, const float* __restrict__ fc1b,
    const ushort_t* __restrict__ w2, const float* __restrict__ bias2,
    float* __restrict__ out) {
    __shared__ __align__(16) ushort_t U[16384];
    __shared__ __align__(16) ushort_t HV[NHEAD][32 * VTS];
    __shared__ float MRm[64];
    __shared__ float MRs[64];
    const int tid = threadIdx.x;
    const int wave = tid >> 6;
    const int lane = tid & 63;
    const int l16 = lane & 15;
    const int quad = lane >> 4;
    const int h = wave;
    const int win = blockIdx.x;
    const int wn = wave * 32;
    const float scale = 0.25503492f;   // 32^-0.5 * log2(e)

    ushort_t* XLN = U;                         // 64 x 136
    char* QK = (char*)(U + h * 4096);          // 64 rows x 128 B, swizzled
    ushort_t* PL = U + h * 4096;               // 64 x 40 (overlays QK, own wave)
    ushort_t* VT = HV[h];
    ushort_t* AH = U;                          // MLP phase: 64 x 136
    ushort_t* PS = (ushort_t*)HV;              // MLP phase: 64 x 136 (8704<=9216)

    // ---- LN1 (4 threads per row, rows >=49 clamped to token 0) ----
    {
        int row = tid >> 2;
        int ch0 = (tid & 3) * 32;
        int t = (row < NN) ? row : 0;
        int gtok = win2tok(win * NN + t);
        const float* xp = x + (size_t)gtok * CC + ch0;
        float v[32];
        float s = 0.f, sq = 0.f;
        #pragma unroll
        for (int i = 0; i < 4; ++i) {
            float4 a0 = *(const float4*)(xp + i * 8);
            float4 a1 = *(const float4*)(xp + i * 8 + 4);
            v[i * 8 + 0] = a0.x; v[i * 8 + 1] = a0.y;
            v[i * 8 + 2] = a0.z; v[i * 8 + 3] = a0.w;
            v[i * 8 + 4] = a1.x; v[i * 8 + 5] = a1.y;
            v[i * 8 + 6] = a1.z; v[i * 8 + 7] = a1.w;
            #pragma unroll
            for (int j = 0; j < 8; ++j) { s += v[i * 8 + j]; sq += v[i * 8 + j] * v[i * 8 + j]; }
        }
        s += __shfl_xor(s, 1);  sq += __shfl_xor(sq, 1);
        s += __shfl_xor(s, 2);  sq += __shfl_xor(sq, 2);
        float mean = s * (1.0f / 128.0f);
        float var = sq * (1.0f / 128.0f) - mean * mean;
        float rstd = rsqrtf(var + 1e-5f);
        #pragma unroll
        for (int i = 0; i < 4; ++i) {
            float n[8];
            #pragma unroll
            for (int j = 0; j < 8; ++j) {
                int c = ch0 + i * 8 + j;
                n[j] = (v[i * 8 + j] - mean) * rstd * g1[c] + b1ln[c];
            }
            uint4 pk4;
            pk4.x = pkbf(n[0], n[1]); pk4.y = pkbf(n[2], n[3]);
            pk4.z = pkbf(n[4], n[5]); pk4.w = pkbf(n[6], n[7]);
            *(uint4*)&XLN[row * 136 + ch0 + i * 8] = pk4;
        }
    }
    __syncthreads();   // XLN ready

    // ---- cache token frags in regs ----
    bf16x8 tf[4][4];
    #pragma unroll
    for (int kk = 0; kk < 4; ++kk)
        #pragma unroll
        for (int i = 0; i < 4; ++i)
            tf[kk][i] = *(const bf16x8*)&XLN[(16 * i + l16) * 136 + kk * 32 + quad * 8];
    __syncthreads();   // XLN dead; U becomes QK region

    // ---- Q (swapped: D^T[qcol][token]), scale(+log2e) folded; j-outer ----
    #pragma unroll
    for (int j = 0; j < 2; ++j) {
        f32x4 s1[4];
        #pragma unroll
        for (int i = 0; i < 4; ++i)
            s1[i] = (f32x4){0.f, 0.f, 0.f, 0.f};
        #pragma unroll
        for (int kk = 0; kk < 4; ++kk) {
            bf16x8 wf = *(const bf16x8*)&wq[(size_t)(h * 32 + 16 * j + l16) * 128 + kk * 32 + quad * 8];
            #pragma unroll
            for (int i = 0; i < 4; ++i)
                s1[i] = __builtin_amdgcn_mfma_f32_16x16x32_bf16(wf, tf[kk][i], s1[i], 0, 0, 0);
        }
        float4 bv = *(const float4*)&qkv_b[h * 32 + 16 * j + quad * 4];
        #pragma unroll
        for (int i = 0; i < 4; ++i) {
            uint2 pk;
            pk.x = pkbf((s1[i][0] + bv.x) * scale, (s1[i][1] + bv.y) * scale);
            pk.y = pkbf((s1[i][2] + bv.z) * scale, (s1[i][3] + bv.w) * scale);
            int row = 16 * i + l16;
            *(uint2*)(QK + row * 128 + ((32 * j + 8 * quad) ^ ((row & 7) << 4))) = pk;
        }
    }
    // ---- K (swapped); j-outer ----
    #pragma unroll
    for (int j = 0; j < 2; ++j) {
        f32x4 s1[4];
        #pragma unroll
        for (int i = 0; i < 4; ++i)
            s1[i] = (f32x4){0.f, 0.f, 0.f, 0.f};
        #pragma unroll
        for (int kk = 0; kk < 4; ++kk) {
            bf16x8 wf = *(const bf16x8*)&wq[(size_t)(128 + h * 32 + 16 * j + l16) * 128 + kk * 32 + quad * 8];
            #pragma unroll
            for (int i = 0; i < 4; ++i)
                s1[i] = __builtin_amdgcn_mfma_f32_16x16x32_bf16(wf, tf[kk][i], s1[i], 0, 0, 0);
        }
        float4 bv = *(const float4*)&qkv_b[128 + h * 32 + 16 * j + quad * 4];
        #pragma unroll
        for (int i = 0; i < 4; ++i) {
            uint2 pk;
            pk.x = pkbf(s1[i][0] + bv.x, s1[i][1] + bv.y);
            pk.y = pkbf(s1[i][2] + bv.z, s1[i][3] + bv.w);
            int row = 16 * i + l16;
            *(uint2*)(QK + row * 128 + ((64 + 32 * j + 8 * quad) ^ ((row & 7) << 4))) = pk;
        }
    }
    // ---- V (non-swapped: D[token][vcol] -> Vt[d][token]); j-outer ----
    #pragma unroll
    for (int j = 0; j < 2; ++j) {
        f32x4 sv[4];
        #pragma unroll
        for (int i = 0; i < 4; ++i)
            sv[i] = (f32x4){0.f, 0.f, 0.f, 0.f};
        #pragma unroll
        for (int kk = 0; kk < 4; ++kk) {
            bf16x8 wf = *(const bf16x8*)&wq[(size_t)(256 + h * 32 + 16 * j + l16) * 128 + kk * 32 + quad * 8];
            #pragma unroll
            for (int i = 0; i < 4; ++i)
                sv[i] = __builtin_amdgcn_mfma_f32_16x16x32_bf16(tf[kk][i], wf, sv[i], 0, 0, 0);
        }
        float bvv = qkv_b[256 + h * 32 + 16 * j + l16];
        #pragma unroll
        for (int i = 0; i < 4; ++i) {
            uint2 pk;
            pk.x = pkbf(sv[i][0] + bvv, sv[i][1] + bvv);
            pk.y = pkbf(sv[i][2] + bvv, sv[i][3] + bvv);
            *(uint2*)&VT[(16 * j + l16) * VTS + 16 * i + quad * 4] = pk;
        }
    }

    // ---- S = QK^T (K dim = HD = 32 exactly) ----
    f32x4 s[4][4];
    {
        bf16x8 qa[4], kb[4];
        #pragma unroll
        for (int t = 0; t < 4; ++t) {
            int row = 16 * t + l16;
            int swz = (row & 7) << 4;
            qa[t] = *(const bf16x8*)(QK + row * 128 + ((16 * quad) ^ swz));
            kb[t] = *(const bf16x8*)(QK + row * 128 + ((64 + 16 * quad) ^ swz));
        }
        #pragma unroll
        for (int mi = 0; mi < 4; ++mi)
            #pragma unroll
            for (int ni = 0; ni < 4; ++ni) {
                f32x4 z = {0.f, 0.f, 0.f, 0.f};
                s[mi][ni] = __builtin_amdgcn_mfma_f32_16x16x32_bf16(qa[mi], kb[ni], z, 0, 0, 0);
            }
    }

    // ---- + relative-position bias (pre-scaled by log2e in prep_all) ----
    const float* bh = bias + h * 4096;
    #pragma unroll
    for (int mi = 0; mi < 4; ++mi)
        #pragma unroll
        for (int ni = 0; ni < 4; ++ni)
            #pragma unroll
            for (int r = 0; r < 4; ++r)
                s[mi][ni][r] += bh[(16 * mi + quad * 4 + r) * 64 + 16 * ni + l16];

    // ---- softmax over cols via raw v_exp (log2e folded into scale+bias;
    //      no max-sub: |scores| << 2, shift-invariant; cols >=49 masked) ----
    #pragma unroll
    for (int mi = 0; mi < 4; ++mi)
        #pragma unroll
        for (int r = 0; r < 4; ++r) {
            float e0 = __builtin_amdgcn_exp2f(s[mi][0][r]);
            float e1 = __builtin_amdgcn_exp2f(s[mi][1][r]);
            float e2 = __builtin_amdgcn_exp2f(s[mi][2][r]);
            float e3 = (l16 == 0) ? __builtin_amdgcn_exp2f(s[mi][3][r]) : 0.f;
            float sum = (e0 + e1) + (e2 + e3);
            sum += __shfl_xor(sum, 1);
            sum += __shfl_xor(sum, 2);
            sum += __shfl_xor(sum, 4);
            sum += __shfl_xor(sum, 8);
            float inv = __builtin_amdgcn_rcpf(sum);
            s[mi][0][r] = e0 * inv;
            s[mi][1][r] = e1 * inv;
            s[mi][2][r] = e2 * inv;
            s[mi][3][r] = e3 * inv;
        }

    // ---- pack P to bf16 regs (frees f32 S before PV) ----
    uint2 pP[4][4];
    #pragma unroll
    for (int mi = 0; mi < 4; ++mi)
        #pragma unroll
        for (int ni = 0; ni < 4; ++ni) {
            pP[mi][ni].x = pkbf(s[mi][ni][0], s[mi][ni][1]);
            pP[mi][ni].y = pkbf(s[mi][ni][2], s[mi][ni][3]);
        }

    // ---- O^T = Vt · P^T, P streamed in two 32-col halves through PL ----
    f32x4 o[2][4];
    #pragma unroll
    for (int k0 = 0; k0 < 64; k0 += 32) {
        int nb = k0 >> 4;
        #pragma unroll
        for (int mi = 0; mi < 4; ++mi)
            #pragma unroll
            for (int nn = 0; nn < 2; ++nn) {
                uint2 pk = pP[mi][nb + nn];
                int base = (16 * mi + quad * 4) * PLS + 16 * nn + l16;
                PL[base] = (ushort_t)pk.x;
                PL[base + PLS] = (ushort_t)(pk.x >> 16);
                PL[base + 2 * PLS] = (ushort_t)pk.y;
                PL[base + 3 * PLS] = (ushort_t)(pk.y >> 16);
            }
        bf16x8 va[2], pb[4];
        #pragma unroll
        for (int it = 0; it < 2; ++it)
            va[it] = *(const bf16x8*)&VT[(16 * it + l16) * VTS + k0 + quad * 8];
        #pragma unroll
        for (int jt = 0; jt < 4; ++jt)
            pb[jt] = *(const bf16x8*)&PL[(16 * jt + l16) * PLS + quad * 8];
        #pragma unroll
        for (int it = 0; it < 2; ++it)
            #pragma unroll
            for (int jt = 0; jt < 4; ++jt) {
                if (k0 == 0) {
                    f32x4 z = {0.f, 0.f, 0.f, 0.f};
                    o[it][jt] = __builtin_amdgcn_mfma_f32_16x16x32_bf16(va[it], pb[jt], z, 0, 0, 0);
                } else {
                    o[it][jt] = __builtin_amdgcn_mfma_f32_16x16x32_bf16(va[it], pb[jt], o[it][jt], 0, 0, 0);
                }
            }
    }
    __syncthreads();   // all waves done reading QK/PL/VT

    // ---- O -> AH (LDS; pkbf pairs). pads are finite token-0 clones ----
    #pragma unroll
    for (int jt = 0; jt < 4; ++jt) {
        int m = 16 * jt + l16;
        #pragma unroll
        for (int it = 0; it < 2; ++it) {
            uint2 st;
            st.x = pkbf(o[it][jt][0], o[it][jt][1]);
            st.y = pkbf(o[it][jt][2], o[it][jt][3]);
            *(uint2*)&AH[m * 136 + h * HD + 16 * it + quad * 4] = st;
        }
    }
    __syncthreads();   // AH (attn result, 64x128) ready

    // ---- prefetch x for LN2 (in flight under proj's MFMA) ----
    float vx[32];
    int row2 = tid >> 2;
    int ch02 = (tid & 3) * 32;
    {
        int t = (row2 < NN) ? row2 : 0;
        int gtok = win2tok(win * NN + t);
        const float* xp = x + (size_t)gtok * CC + ch02;
        #pragma unroll
        for (int i = 0; i < 8; ++i) {
            float4 a = *(const float4*)(xp + i * 4);
            vx[i * 4 + 0] = a.x; vx[i * 4 + 1] = a.y;
            vx[i * 4 + 2] = a.z; vx[i * 4 + 3] = a.w;
        }
    }

    // ---- proj: AH -> PS (bf16 64x136) ----
    {
        f32x4 pa[2][4];
        #pragma unroll
        for (int j = 0; j < 2; ++j)
            #pragma unroll
            for (int i = 0; i < 4; ++i)
                pa[j][i] = (f32x4){0.f, 0.f, 0.f, 0.f};
        #pragma unroll
        for (int kk = 0; kk < 4; ++kk) {
            bf16x8 af[4];
            #pragma unroll
            for (int i = 0; i < 4; ++i)
                af[i] = *(const bf16x8*)&AH[(16 * i + l16) * 136 + kk * 32 + quad * 8];
            #pragma unroll
            for (int j = 0; j < 2; ++j) {
                bf16x8 wf = *(const bf16x8*)&wp[(size_t)(wn + 16 * j + l16) * 128 + kk * 32 + quad * 8];
                #pragma unroll
                for (int i = 0; i < 4; ++i)
                    pa[j][i] = __builtin_amdgcn_mfma_f32_16x16x32_bf16(wf, af[i], pa[j][i], 0, 0, 0);
            }
        }
        #pragma unroll
        for (int j = 0; j < 2; ++j) {
            float4 bv = *(const float4*)&proj_b[wn + 16 * j + quad * 4];
            #pragma unroll
            for (int i = 0; i < 4; ++i) {
                uint2 pk;
                pk.x = pkbf(pa[j][i][0] + bv.x, pa[j][i][1] + bv.y);
                pk.y = pkbf(pa[j][i][2] + bv.z, pa[j][i][3] + bv.w);
                *(uint2*)&PS[(16 * i + l16) * 136 + wn + 16 * j + quad * 4] = pk;
            }
        }
    }
    __syncthreads();   // PS (proj result) ready; AH free for h2

    // ---- residual + LN2: h2 -> AH (bf16), (mean, sd) -> MR ----
    {
        float s2 = 0.f, sq = 0.f;
        #pragma unroll
        for (int i = 0; i < 4; ++i) {
            ushort4 p0 = *(const ushort4*)&PS[row2 * 136 + ch02 + i * 8];
            ushort4 p1 = *(const ushort4*)&PS[row2 * 136 + ch02 + i * 8 + 4];
            vx[i * 8 + 0] += bf2f(p0.x); vx[i * 8 + 1] += bf2f(p0.y);
            vx[i * 8 + 2] += bf2f(p0.z); vx[i * 8 + 3] += bf2f(p0.w);
            vx[i * 8 + 4] += bf2f(p1.x); vx[i * 8 + 5] += bf2f(p1.y);
            vx[i * 8 + 6] += bf2f(p1.z); vx[i * 8 + 7] += bf2f(p1.w);
            #pragma unroll
            for (int j = 0; j < 8; ++j) { s2 += vx[i * 8 + j]; sq += vx[i * 8 + j] * vx[i * 8 + j]; }
        }
        s2 += __shfl_xor(s2, 1);  sq += __shfl_xor(sq, 1);
        s2 += __shfl_xor(s2, 2);  sq += __shfl_xor(sq, 2);
        float mean = s2 * (1.0f / 128.0f);
        float var = sq * (1.0f / 128.0f) - mean * mean;
        float rstd = rsqrtf(var + 1e-5f);
        if ((tid & 3) == 0) {
            MRm[row2] = mean;
            MRs[row2] = (var + 1e-5f) * rstd;   // = sqrt(var+eps) = 1/rstd
        }
        #pragma unroll
        for (int i = 0; i < 4; ++i) {
            float n[8];
            #pragma unroll
            for (int j = 0; j < 8; ++j) {
                int c = ch02 + i * 8 + j;
                n[j] = (vx[i * 8 + j] - mean) * rstd * g2[c] + b2[c];
            }
            uint4 pk4;
            pk4.x = pkbf(n[0], n[1]); pk4.y = pkbf(n[2], n[3]);
            pk4.z = pkbf(n[4], n[5]); pk4.w = pkbf(n[6], n[7]);
            *(uint4*)&AH[row2 * 136 + ch02 + i * 8] = pk4;
        }
    }
    __syncthreads();   // AH = h2 ready; PS consumed

    // ---- MLP c-loop ----
    f32x4 acc2[2][4];
    #pragma unroll
    for (int j = 0; j < 2; ++j)
        #pragma unroll
        for (int i = 0; i < 4; ++i)
            acc2[j][i] = (f32x4){0.f, 0.f, 0.f, 0.f};

    for (int c = 0; c < 4; ++c) {
        f32x4 s1[2][4];
        #pragma unroll
        for (int j = 0; j < 2; ++j)
            #pragma unroll
            for (int i = 0; i < 4; ++i)
                s1[j][i] = (f32x4){0.f, 0.f, 0.f, 0.f};
        #pragma unroll
        for (int kk = 0; kk < 4; ++kk) {
            bf16x8 hf[4];
            #pragma unroll
            for (int i = 0; i < 4; ++i)
                hf[i] = *(const bf16x8*)&AH[(16 * i + l16) * 136 + kk * 32 + quad * 8];
            #pragma unroll
            for (int j = 0; j < 2; ++j) {
                bf16x8 wf = *(const bf16x8*)&w1[(size_t)(c * 128 + wn + 16 * j + l16) * 128 + kk * 32 + quad * 8];
                #pragma unroll
                for (int i = 0; i < 4; ++i)
                    s1[j][i] = __builtin_amdgcn_mfma_f32_16x16x32_bf16(wf, hf[i], s1[j][i], 0, 0, 0);
            }
        }
        uint2 pk[2][4];
        #pragma unroll
        for (int j = 0; j < 2; ++j) {
            float4 bv = *(const float4*)&fc1b[c * 128 + wn + 16 * j + quad * 4];
            #pragma unroll
            for (int i = 0; i < 4; ++i) {
                float g[4];
                #pragma unroll
                for (int r = 0; r < 4; ++r) {
                    float u = s1[j][i][r] + ((const float*)&bv)[r];
                    float u2 = u * u;
                    float z2 = u * __builtin_fmaf(0.10294324f, u2, 2.3022084f);
                    float e = __builtin_amdgcn_exp2f(-z2);
                    g[r] = u * __builtin_amdgcn_rcpf(1.0f + e);
                }
                pk[j][i].x = pkbf(g[0], g[1]);
                pk[j][i].y = pkbf(g[2], g[3]);
            }
        }
        __syncthreads();
        #pragma unroll
        for (int j = 0; j < 2; ++j)
            #pragma unroll
            for (int i = 0; i < 4; ++i)
                *(uint2*)&PS[(16 * i + l16) * 136 + wn + 16 * j + quad * 4] = pk[j][i];
        __syncthreads();
        #pragma unroll
        for (int kk = 0; kk < 4; ++kk) {
            bf16x8 pf[4];
            #pragma unroll
            for (int i = 0; i < 4; ++i)
                pf[i] = *(const bf16x8*)&PS[(16 * i + l16) * 136 + kk * 32 + quad * 8];
            #pragma unroll
            for (int j = 0; j < 2; ++j) {
                bf16x8 wf = *(const bf16x8*)&w2[(size_t)(wn + 16 * j + l16) * 512 + c * 128 + kk * 32 + quad * 8];
                #pragma unroll
                for (int i = 0; i < 4; ++i)
                    acc2[j][i] = __builtin_amdgcn_mfma_f32_16x16x32_bf16(wf, pf[i], acc2[j][i], 0, 0, 0);
            }
        }
    }

    // ---- epilogue: x2 = (h2 - b2)*sd/g2 + mean; out = x2 + mlp + bias2 ----
    float invg[2][4], b2v[2][4];
    #pragma unroll
    for (int j = 0; j < 2; ++j) {
        float4 gv = *(const float4*)&g2[wn + 16 * j + quad * 4];
        float4 bv = *(const float4*)&b2[wn + 16 * j + quad * 4];
        invg[j][0] = __builtin_amdgcn_rcpf(gv.x);
        invg[j][1] = __builtin_amdgcn_rcpf(gv.y);
        invg[j][2] = __builtin_amdgcn_rcpf(gv.z);
        invg[j][3] = __builtin_amdgcn_rcpf(gv.w);
        b2v[j][0] = bv.x; b2v[j][1] = bv.y; b2v[j][2] = bv.z; b2v[j][3] = bv.w;
    }
    #pragma unroll
    for (int i = 0; i < 4; ++i) {
        int row = 16 * i + l16;
        if (row < NN) {
            int gtok = win2tok(win * NN + row);
            float mean = MRm[row];
            float sd = MRs[row];
            #pragma unroll
            for (int j = 0; j < 2; ++j) {
                float4 bb = *(const float4*)&bias2[wn + 16 * j + quad * 4];
                ushort4 hv = *(const ushort4*)&AH[row * 136 + wn + 16 * j + quad * 4];
                float4 cur;
                cur.x = (bf2f(hv.x) - b2v[j][0]) * (invg[j][0] * sd) + mean + acc2[j][i][0] + bb.x;
                cur.y = (bf2f(hv.y) - b2v[j][1]) * (invg[j][1] * sd) + mean + acc2[j][i][1] + bb.y;
                cur.z = (bf2f(hv.z) - b2v[j][2]) * (invg[j][2] * sd) + mean + acc2[j][i][2] + bb.z;
                cur.w = (bf2f(hv.w) - b2v[j][3]) * (invg[j][3] * sd) + mean + acc2[j][i][3] + bb.w;
                *(float4*)(out + (size_t)gtok * CC + wn + 16 * j + quad * 4) = cur;
            }
        }
    }
}

// ============ launch ============
extern "C" void kernel_launch(void* const* d_in, const int* in_sizes, int n_in,
                              void* d_out, int out_size, void* d_ws, size_t ws_size,
                              hipStream_t stream) {
    const float* x       = (const float*)d_in[0];
    const float* norm1_g = (const float*)d_in[1];
    const float* norm1_b = (const float*)d_in[2];
    const float* qkv_w   = (const float*)d_in[3];
    const float* qkv_b   = (const float*)d_in[4];
    const float* rpb     = (const float*)d_in[5];
    const float* proj_w  = (const float*)d_in[6];
    const float* proj_b  = (const float*)d_in[7];
    const float* norm2_g = (const float*)d_in[8];
    const float* norm2_b = (const float*)d_in[9];
    const float* fc1_w   = (const float*)d_in[10];
    const float* fc1_b   = (const float*)d_in[11];
    const float* fc2_w   = (const float*)d_in[12];
    const float* fc2_b   = (const float*)d_in[13];
    const int*   rel_idx = (const int*)d_in[14];

    char* ws = (char*)d_ws;
    float*    biasT = (float*)ws;
    ushort_t* wall  = (ushort_t*)(ws + 65536);
    ushort_t* wqkv  = wall;
    ushort_t* wproj = wall + 49152;
    ushort_t* wfc1  = wall + 65536;
    ushort_t* wfc2  = wall + 131072;

    prep_all<<<dim3(772), dim3(256), 0, stream>>>(
        qkv_w, proj_w, fc1_w, fc2_w, wall, rpb, rel_idx, biasT);
    swin_fused<<<dim3(NWIN), dim3(256), 0, stream>>>(
        x, norm1_g, norm1_b, wqkv, qkv_b, biasT,
        wproj, proj_b, norm2_g, norm2_b,
        wfc1, fc1_b, wfc2, fc2_b, (float*)d_out);
}

// Round 15
// 343.295 us; speedup vs baseline: 1.0041x; 1.0041x over previous
//
#include <hip/hip_runtime.h>

typedef unsigned short ushort_t;
typedef unsigned int uint_t;

typedef __bf16 bf16x8 __attribute__((ext_vector_type(8)));
typedef float f32x4 __attribute__((ext_vector_type(4)));

static __device__ __forceinline__ float bf2f(ushort_t h) {
    return __uint_as_float(((uint_t)h) << 16);
}
static __device__ __forceinline__ ushort_t f2bf(float f) {
    uint_t u = __float_as_uint(f);
    u = u + 0x7FFFu + ((u >> 16) & 1u);
    return (ushort_t)(u >> 16);
}
// pack two floats as bf16 (round-half-up) into one dword: low=lo, high=hi
static __device__ __forceinline__ uint_t pkbf(float lo, float hi) {
    uint_t a = __float_as_uint(lo) + 0x8000u;
    uint_t b = __float_as_uint(hi) + 0x8000u;
    return __builtin_amdgcn_perm(b, a, 0x07060302u);
}

// ---------------- constants ----------------
#define BB 32
#define HH 56
#define WW_ 56
#define CC 128
#define NHEAD 4
#define WS 7
#define SS 3
#define LL (HH * WW_)           // 3136
#define NTOK (BB * LL)          // 100352
#define NWIN (BB * 64)          // 2048
#define NN 49
#define HD 32
#define PLS 40                  // P half LDS stride (shorts) — conflict-free
#define VTS 72                  // Vt LDS stride (shorts) — conflict-free

// windowed token -> global token (shift map)
static __device__ __forceinline__ int win2tok(int wid) {
    int win = wid / NN, t = wid - win * NN;
    int bb = win >> 6, wrem = win & 63;
    int wi = wrem >> 3, wj = wrem & 7;
    int ti = t / WS, tj = t - ti * WS;
    int hh = wi * WS + ti + SS; if (hh >= HH) hh -= HH;
    int ww = wj * WS + tj + SS; if (ww >= WW_) ww -= WW_;
    return bb * LL + hh * WW_ + ww;
}

// ============ merged prep: weights fp32->bf16 (blocks 0..767) +
//              bias table x log2(e) (blocks 768..771) ============
__global__ __launch_bounds__(256) void prep_all(
    const float* __restrict__ qkv_w, const float* __restrict__ proj_w,
    const float* __restrict__ fc1_w, const float* __restrict__ fc2_w,
    ushort_t* __restrict__ dst,
    const float* __restrict__ rpb, const int* __restrict__ rel_idx,
    float* __restrict__ bias) {
    int b = blockIdx.x;
    if (b < 768) {
        int i = b * 256 + threadIdx.x;   // 0 .. 196607
        const float* src;
        int off;
        if (i < 49152)        { src = qkv_w;  off = i; }
        else if (i < 65536)   { src = proj_w; off = i - 49152; }
        else if (i < 131072)  { src = fc1_w;  off = i - 65536; }
        else                  { src = fc2_w;  off = i - 131072; }
        dst[i] = f2bf(src[off]);
    } else {
        int h = b - 768;
        for (int idx = threadIdx.x; idx < 4096; idx += 256) {
            int i = idx >> 6, j = idx & 63;
            float v = 0.f;
            if (i < NN && j < NN)
                v = rpb[(size_t)rel_idx[i * NN + j] * NHEAD + h] * 1.4426950409f;
            bias[h * 4096 + idx] = v;
        }
    }
}

// ============ fully-fused: LN1+QKV+attn+proj+residual+LN2+MLP ============
// r15 = r13 checkpoint (176.6 us, VGPR 124) + ONLY the register-neutral
// pkbf pair-packing in LN1 / O-store / LN2 (local temporaries packed at
// the same program point; no cross-phase liveness).
// r14's vx[32] LN2-prefetch REVERTED: 32 VGPRs live across proj pushed
// the peak 124->140 over the 128 cliff (occ 21.6->11.7, dur +107 us) —
// same failure mode as r5. Rule: nothing crosses a phase boundary in regs.
// Base: r10 structure (QK swizzle, Vt in LDS, 3 blocks/CU) + r13 exp2.
__global__ __launch_bounds__(256) void swin_fused(
    const float* __restrict__ x, const float* __restrict__ g1,
    const float* __restrict__ b1ln, const ushort_t* __restrict__ wq,
    const float* __restrict__ qkv_b, const float* __restrict__ bias,
    const ushort_t* __restrict__ wp, const float* __restrict__ proj_b,
    const float* __restrict__ g2, const float* __restrict__ b2,
    const ushort_t* __restrict__ w1, const float* __restrict__ fc1b,
    const ushort_t* __restrict__ w2, const float* __restrict__ bias2,
    float* __restrict__ out) {
    __shared__ __align__(16) ushort_t U[16384];
    __shared__ __align__(16) ushort_t HV[NHEAD][32 * VTS];
    __shared__ float MRm[64];
    __shared__ float MRs[64];
    const int tid = threadIdx.x;
    const int wave = tid >> 6;
    const int lane = tid & 63;
    const int l16 = lane & 15;
    const int quad = lane >> 4;
    const int h = wave;
    const int win = blockIdx.x;
    const int wn = wave * 32;
    const float scale = 0.25503492f;   // 32^-0.5 * log2(e)

    ushort_t* XLN = U;                         // 64 x 136
    char* QK = (char*)(U + h * 4096);          // 64 rows x 128 B, swizzled
    ushort_t* PL = U + h * 4096;               // 64 x 40 (overlays QK, own wave)
    ushort_t* VT = HV[h];
    ushort_t* AH = U;                          // MLP phase: 64 x 136
    ushort_t* PS = (ushort_t*)HV;              // MLP phase: 64 x 136 (8704<=9216)

    // ---- LN1 (4 threads per row, rows >=49 clamped to token 0) ----
    {
        int row = tid >> 2;
        int ch0 = (tid & 3) * 32;
        int t = (row < NN) ? row : 0;
        int gtok = win2tok(win * NN + t);
        const float* xp = x + (size_t)gtok * CC + ch0;
        float v[32];
        float s = 0.f, sq = 0.f;
        #pragma unroll
        for (int i = 0; i < 4; ++i) {
            float4 a0 = *(const float4*)(xp + i * 8);
            float4 a1 = *(const float4*)(xp + i * 8 + 4);
            v[i * 8 + 0] = a0.x; v[i * 8 + 1] = a0.y;
            v[i * 8 + 2] = a0.z; v[i * 8 + 3] = a0.w;
            v[i * 8 + 4] = a1.x; v[i * 8 + 5] = a1.y;
            v[i * 8 + 6] = a1.z; v[i * 8 + 7] = a1.w;
            #pragma unroll
            for (int j = 0; j < 8; ++j) { s += v[i * 8 + j]; sq += v[i * 8 + j] * v[i * 8 + j]; }
        }
        s += __shfl_xor(s, 1);  sq += __shfl_xor(sq, 1);
        s += __shfl_xor(s, 2);  sq += __shfl_xor(sq, 2);
        float mean = s * (1.0f / 128.0f);
        float var = sq * (1.0f / 128.0f) - mean * mean;
        float rstd = rsqrtf(var + 1e-5f);
        #pragma unroll
        for (int i = 0; i < 4; ++i) {
            float n[8];
            #pragma unroll
            for (int j = 0; j < 8; ++j) {
                int c = ch0 + i * 8 + j;
                n[j] = (v[i * 8 + j] - mean) * rstd * g1[c] + b1ln[c];
            }
            uint4 pk4;
            pk4.x = pkbf(n[0], n[1]); pk4.y = pkbf(n[2], n[3]);
            pk4.z = pkbf(n[4], n[5]); pk4.w = pkbf(n[6], n[7]);
            *(uint4*)&XLN[row * 136 + ch0 + i * 8] = pk4;
        }
    }
    __syncthreads();   // XLN ready

    // ---- cache token frags in regs ----
    bf16x8 tf[4][4];
    #pragma unroll
    for (int kk = 0; kk < 4; ++kk)
        #pragma unroll
        for (int i = 0; i < 4; ++i)
            tf[kk][i] = *(const bf16x8*)&XLN[(16 * i + l16) * 136 + kk * 32 + quad * 8];
    __syncthreads();   // XLN dead; U becomes QK region

    // ---- Q (swapped: D^T[qcol][token]), scale(+log2e) folded; j-outer ----
    #pragma unroll
    for (int j = 0; j < 2; ++j) {
        f32x4 s1[4];
        #pragma unroll
        for (int i = 0; i < 4; ++i)
            s1[i] = (f32x4){0.f, 0.f, 0.f, 0.f};
        #pragma unroll
        for (int kk = 0; kk < 4; ++kk) {
            bf16x8 wf = *(const bf16x8*)&wq[(size_t)(h * 32 + 16 * j + l16) * 128 + kk * 32 + quad * 8];
            #pragma unroll
            for (int i = 0; i < 4; ++i)
                s1[i] = __builtin_amdgcn_mfma_f32_16x16x32_bf16(wf, tf[kk][i], s1[i], 0, 0, 0);
        }
        float4 bv = *(const float4*)&qkv_b[h * 32 + 16 * j + quad * 4];
        #pragma unroll
        for (int i = 0; i < 4; ++i) {
            uint2 pk;
            pk.x = pkbf((s1[i][0] + bv.x) * scale, (s1[i][1] + bv.y) * scale);
            pk.y = pkbf((s1[i][2] + bv.z) * scale, (s1[i][3] + bv.w) * scale);
            int row = 16 * i + l16;
            *(uint2*)(QK + row * 128 + ((32 * j + 8 * quad) ^ ((row & 7) << 4))) = pk;
        }
    }
    // ---- K (swapped); j-outer ----
    #pragma unroll
    for (int j = 0; j < 2; ++j) {
        f32x4 s1[4];
        #pragma unroll
        for (int i = 0; i < 4; ++i)
            s1[i] = (f32x4){0.f, 0.f, 0.f, 0.f};
        #pragma unroll
        for (int kk = 0; kk < 4; ++kk) {
            bf16x8 wf = *(const bf16x8*)&wq[(size_t)(128 + h * 32 + 16 * j + l16) * 128 + kk * 32 + quad * 8];
            #pragma unroll
            for (int i = 0; i < 4; ++i)
                s1[i] = __builtin_amdgcn_mfma_f32_16x16x32_bf16(wf, tf[kk][i], s1[i], 0, 0, 0);
        }
        float4 bv = *(const float4*)&qkv_b[128 + h * 32 + 16 * j + quad * 4];
        #pragma unroll
        for (int i = 0; i < 4; ++i) {
            uint2 pk;
            pk.x = pkbf(s1[i][0] + bv.x, s1[i][1] + bv.y);
            pk.y = pkbf(s1[i][2] + bv.z, s1[i][3] + bv.w);
            int row = 16 * i + l16;
            *(uint2*)(QK + row * 128 + ((64 + 32 * j + 8 * quad) ^ ((row & 7) << 4))) = pk;
        }
    }
    // ---- V (non-swapped: D[token][vcol] -> Vt[d][token]); j-outer ----
    #pragma unroll
    for (int j = 0; j < 2; ++j) {
        f32x4 sv[4];
        #pragma unroll
        for (int i = 0; i < 4; ++i)
            sv[i] = (f32x4){0.f, 0.f, 0.f, 0.f};
        #pragma unroll
        for (int kk = 0; kk < 4; ++kk) {
            bf16x8 wf = *(const bf16x8*)&wq[(size_t)(256 + h * 32 + 16 * j + l16) * 128 + kk * 32 + quad * 8];
            #pragma unroll
            for (int i = 0; i < 4; ++i)
                sv[i] = __builtin_amdgcn_mfma_f32_16x16x32_bf16(tf[kk][i], wf, sv[i], 0, 0, 0);
        }
        float bvv = qkv_b[256 + h * 32 + 16 * j + l16];
        #pragma unroll
        for (int i = 0; i < 4; ++i) {
            uint2 pk;
            pk.x = pkbf(sv[i][0] + bvv, sv[i][1] + bvv);
            pk.y = pkbf(sv[i][2] + bvv, sv[i][3] + bvv);
            *(uint2*)&VT[(16 * j + l16) * VTS + 16 * i + quad * 4] = pk;
        }
    }

    // ---- S = QK^T (K dim = HD = 32 exactly) ----
    f32x4 s[4][4];
    {
        bf16x8 qa[4], kb[4];
        #pragma unroll
        for (int t = 0; t < 4; ++t) {
            int row = 16 * t + l16;
            int swz = (row & 7) << 4;
            qa[t] = *(const bf16x8*)(QK + row * 128 + ((16 * quad) ^ swz));
            kb[t] = *(const bf16x8*)(QK + row * 128 + ((64 + 16 * quad) ^ swz));
        }
        #pragma unroll
        for (int mi = 0; mi < 4; ++mi)
            #pragma unroll
            for (int ni = 0; ni < 4; ++ni) {
                f32x4 z = {0.f, 0.f, 0.f, 0.f};
                s[mi][ni] = __builtin_amdgcn_mfma_f32_16x16x32_bf16(qa[mi], kb[ni], z, 0, 0, 0);
            }
    }

    // ---- + relative-position bias (pre-scaled by log2e in prep_all) ----
    const float* bh = bias + h * 4096;
    #pragma unroll
    for (int mi = 0; mi < 4; ++mi)
        #pragma unroll
        for (int ni = 0; ni < 4; ++ni)
            #pragma unroll
            for (int r = 0; r < 4; ++r)
                s[mi][ni][r] += bh[(16 * mi + quad * 4 + r) * 64 + 16 * ni + l16];

    // ---- softmax over cols via raw v_exp (log2e folded into scale+bias;
    //      no max-sub: |scores| << 2, shift-invariant; cols >=49 masked) ----
    #pragma unroll
    for (int mi = 0; mi < 4; ++mi)
        #pragma unroll
        for (int r = 0; r < 4; ++r) {
            float e0 = __builtin_amdgcn_exp2f(s[mi][0][r]);
            float e1 = __builtin_amdgcn_exp2f(s[mi][1][r]);
            float e2 = __builtin_amdgcn_exp2f(s[mi][2][r]);
            float e3 = (l16 == 0) ? __builtin_amdgcn_exp2f(s[mi][3][r]) : 0.f;
            float sum = (e0 + e1) + (e2 + e3);
            sum += __shfl_xor(sum, 1);
            sum += __shfl_xor(sum, 2);
            sum += __shfl_xor(sum, 4);
            sum += __shfl_xor(sum, 8);
            float inv = __builtin_amdgcn_rcpf(sum);
            s[mi][0][r] = e0 * inv;
            s[mi][1][r] = e1 * inv;
            s[mi][2][r] = e2 * inv;
            s[mi][3][r] = e3 * inv;
        }

    // ---- pack P to bf16 regs (frees f32 S before PV) ----
    uint2 pP[4][4];
    #pragma unroll
    for (int mi = 0; mi < 4; ++mi)
        #pragma unroll
        for (int ni = 0; ni < 4; ++ni) {
            pP[mi][ni].x = pkbf(s[mi][ni][0], s[mi][ni][1]);
            pP[mi][ni].y = pkbf(s[mi][ni][2], s[mi][ni][3]);
        }

    // ---- O^T = Vt · P^T, P streamed in two 32-col halves through PL ----
    f32x4 o[2][4];
    #pragma unroll
    for (int k0 = 0; k0 < 64; k0 += 32) {
        int nb = k0 >> 4;
        #pragma unroll
        for (int mi = 0; mi < 4; ++mi)
            #pragma unroll
            for (int nn = 0; nn < 2; ++nn) {
                uint2 pk = pP[mi][nb + nn];
                int base = (16 * mi + quad * 4) * PLS + 16 * nn + l16;
                PL[base] = (ushort_t)pk.x;
                PL[base + PLS] = (ushort_t)(pk.x >> 16);
                PL[base + 2 * PLS] = (ushort_t)pk.y;
                PL[base + 3 * PLS] = (ushort_t)(pk.y >> 16);
            }
        bf16x8 va[2], pb[4];
        #pragma unroll
        for (int it = 0; it < 2; ++it)
            va[it] = *(const bf16x8*)&VT[(16 * it + l16) * VTS + k0 + quad * 8];
        #pragma unroll
        for (int jt = 0; jt < 4; ++jt)
            pb[jt] = *(const bf16x8*)&PL[(16 * jt + l16) * PLS + quad * 8];
        #pragma unroll
        for (int it = 0; it < 2; ++it)
            #pragma unroll
            for (int jt = 0; jt < 4; ++jt) {
                if (k0 == 0) {
                    f32x4 z = {0.f, 0.f, 0.f, 0.f};
                    o[it][jt] = __builtin_amdgcn_mfma_f32_16x16x32_bf16(va[it], pb[jt], z, 0, 0, 0);
                } else {
                    o[it][jt] = __builtin_amdgcn_mfma_f32_16x16x32_bf16(va[it], pb[jt], o[it][jt], 0, 0, 0);
                }
            }
    }
    __syncthreads();   // all waves done reading QK/PL/VT

    // ---- O -> AH (LDS; pkbf pairs). pads are finite token-0 clones ----
    #pragma unroll
    for (int jt = 0; jt < 4; ++jt) {
        int m = 16 * jt + l16;
        #pragma unroll
        for (int it = 0; it < 2; ++it) {
            uint2 st;
            st.x = pkbf(o[it][jt][0], o[it][jt][1]);
            st.y = pkbf(o[it][jt][2], o[it][jt][3]);
            *(uint2*)&AH[m * 136 + h * HD + 16 * it + quad * 4] = st;
        }
    }
    __syncthreads();   // AH (attn result, 64x128) ready

    // ---- proj: AH -> PS (bf16 64x136) ----
    {
        f32x4 pa[2][4];
        #pragma unroll
        for (int j = 0; j < 2; ++j)
            #pragma unroll
            for (int i = 0; i < 4; ++i)
                pa[j][i] = (f32x4){0.f, 0.f, 0.f, 0.f};
        #pragma unroll
        for (int kk = 0; kk < 4; ++kk) {
            bf16x8 af[4];
            #pragma unroll
            for (int i = 0; i < 4; ++i)
                af[i] = *(const bf16x8*)&AH[(16 * i + l16) * 136 + kk * 32 + quad * 8];
            #pragma unroll
            for (int j = 0; j < 2; ++j) {
                bf16x8 wf = *(const bf16x8*)&wp[(size_t)(wn + 16 * j + l16) * 128 + kk * 32 + quad * 8];
                #pragma unroll
                for (int i = 0; i < 4; ++i)
                    pa[j][i] = __builtin_amdgcn_mfma_f32_16x16x32_bf16(wf, af[i], pa[j][i], 0, 0, 0);
            }
        }
        #pragma unroll
        for (int j = 0; j < 2; ++j) {
            float4 bv = *(const float4*)&proj_b[wn + 16 * j + quad * 4];
            #pragma unroll
            for (int i = 0; i < 4; ++i) {
                uint2 pk;
                pk.x = pkbf(pa[j][i][0] + bv.x, pa[j][i][1] + bv.y);
                pk.y = pkbf(pa[j][i][2] + bv.z, pa[j][i][3] + bv.w);
                *(uint2*)&PS[(16 * i + l16) * 136 + wn + 16 * j + quad * 4] = pk;
            }
        }
    }
    __syncthreads();   // PS (proj result) ready; AH free for h2

    // ---- residual + LN2: h2 -> AH (bf16), (mean, sd) -> MR ----
    {
        int row = tid >> 2;
        int ch0 = (tid & 3) * 32;
        int t = (row < NN) ? row : 0;
        int gtok = win2tok(win * NN + t);
        const float* xp = x + (size_t)gtok * CC + ch0;
        float v[32];
        float s2 = 0.f, sq = 0.f;
        #pragma unroll
        for (int i = 0; i < 4; ++i) {
            float4 a0 = *(const float4*)(xp + i * 8);
            float4 a1 = *(const float4*)(xp + i * 8 + 4);
            ushort4 p0 = *(const ushort4*)&PS[row * 136 + ch0 + i * 8];
            ushort4 p1 = *(const ushort4*)&PS[row * 136 + ch0 + i * 8 + 4];
            v[i * 8 + 0] = a0.x + bf2f(p0.x); v[i * 8 + 1] = a0.y + bf2f(p0.y);
            v[i * 8 + 2] = a0.z + bf2f(p0.z); v[i * 8 + 3] = a0.w + bf2f(p0.w);
            v[i * 8 + 4] = a1.x + bf2f(p1.x); v[i * 8 + 5] = a1.y + bf2f(p1.y);
            v[i * 8 + 6] = a1.z + bf2f(p1.z); v[i * 8 + 7] = a1.w + bf2f(p1.w);
            #pragma unroll
            for (int j = 0; j < 8; ++j) { s2 += v[i * 8 + j]; sq += v[i * 8 + j] * v[i * 8 + j]; }
        }
        s2 += __shfl_xor(s2, 1);  sq += __shfl_xor(sq, 1);
        s2 += __shfl_xor(s2, 2);  sq += __shfl_xor(sq, 2);
        float mean = s2 * (1.0f / 128.0f);
        float var = sq * (1.0f / 128.0f) - mean * mean;
        float rstd = rsqrtf(var + 1e-5f);
        if ((tid & 3) == 0) {
            MRm[row] = mean;
            MRs[row] = (var + 1e-5f) * rstd;   // = sqrt(var+eps) = 1/rstd
        }
        #pragma unroll
        for (int i = 0; i < 4; ++i) {
            float n[8];
            #pragma unroll
            for (int j = 0; j < 8; ++j) {
                int c = ch0 + i * 8 + j;
                n[j] = (v[i * 8 + j] - mean) * rstd * g2[c] + b2[c];
            }
            uint4 pk4;
            pk4.x = pkbf(n[0], n[1]); pk4.y = pkbf(n[2], n[3]);
            pk4.z = pkbf(n[4], n[5]); pk4.w = pkbf(n[6], n[7]);
            *(uint4*)&AH[row * 136 + ch0 + i * 8] = pk4;
        }
    }
    __syncthreads();   // AH = h2 ready; PS consumed

    // ---- MLP c-loop ----
    f32x4 acc2[2][4];
    #pragma unroll
    for (int j = 0; j < 2; ++j)
        #pragma unroll
        for (int i = 0; i < 4; ++i)
            acc2[j][i] = (f32x4){0.f, 0.f, 0.f, 0.f};

    for (int c = 0; c < 4; ++c) {
        f32x4 s1[2][4];
        #pragma unroll
        for (int j = 0; j < 2; ++j)
            #pragma unroll
            for (int i = 0; i < 4; ++i)
                s1[j][i] = (f32x4){0.f, 0.f, 0.f, 0.f};
        #pragma unroll
        for (int kk = 0; kk < 4; ++kk) {
            bf16x8 hf[4];
            #pragma unroll
            for (int i = 0; i < 4; ++i)
                hf[i] = *(const bf16x8*)&AH[(16 * i + l16) * 136 + kk * 32 + quad * 8];
            #pragma unroll
            for (int j = 0; j < 2; ++j) {
                bf16x8 wf = *(const bf16x8*)&w1[(size_t)(c * 128 + wn + 16 * j + l16) * 128 + kk * 32 + quad * 8];
                #pragma unroll
                for (int i = 0; i < 4; ++i)
                    s1[j][i] = __builtin_amdgcn_mfma_f32_16x16x32_bf16(wf, hf[i], s1[j][i], 0, 0, 0);
            }
        }
        uint2 pk[2][4];
        #pragma unroll
        for (int j = 0; j < 2; ++j) {
            float4 bv = *(const float4*)&fc1b[c * 128 + wn + 16 * j + quad * 4];
            #pragma unroll
            for (int i = 0; i < 4; ++i) {
                float g[4];
                #pragma unroll
                for (int r = 0; r < 4; ++r) {
                    float u = s1[j][i][r] + ((const float*)&bv)[r];
                    float u2 = u * u;
                    float z2 = u * __builtin_fmaf(0.10294324f, u2, 2.3022084f);
                    float e = __builtin_amdgcn_exp2f(-z2);
                    g[r] = u * __builtin_amdgcn_rcpf(1.0f + e);
                }
                pk[j][i].x = pkbf(g[0], g[1]);
                pk[j][i].y = pkbf(g[2], g[3]);
            }
        }
        __syncthreads();
        #pragma unroll
        for (int j = 0; j < 2; ++j)
            #pragma unroll
            for (int i = 0; i < 4; ++i)
                *(uint2*)&PS[(16 * i + l16) * 136 + wn + 16 * j + quad * 4] = pk[j][i];
        __syncthreads();
        #pragma unroll
        for (int kk = 0; kk < 4; ++kk) {
            bf16x8 pf[4];
            #pragma unroll
            for (int i = 0; i < 4; ++i)
                pf[i] = *(const bf16x8*)&PS[(16 * i + l16) * 136 + kk * 32 + quad * 8];
            #pragma unroll
            for (int j = 0; j < 2; ++j) {
                bf16x8 wf = *(const bf16x8*)&w2[(size_t)(wn + 16 * j + l16) * 512 + c * 128 + kk * 32 + quad * 8];
                #pragma unroll
                for (int i = 0; i < 4; ++i)
                    acc2[j][i] = __builtin_amdgcn_mfma_f32_16x16x32_bf16(wf, pf[i], acc2[j][i], 0, 0, 0);
            }
        }
    }

    // ---- epilogue: x2 = (h2 - b2)*sd/g2 + mean; out = x2 + mlp + bias2 ----
    float invg[2][4], b2v[2][4];
    #pragma unroll
    for (int j = 0; j < 2; ++j) {
        float4 gv = *(const float4*)&g2[wn + 16 * j + quad * 4];
        float4 bv = *(const float4*)&b2[wn + 16 * j + quad * 4];
        invg[j][0] = __builtin_amdgcn_rcpf(gv.x);
        invg[j][1] = __builtin_amdgcn_rcpf(gv.y);
        invg[j][2] = __builtin_amdgcn_rcpf(gv.z);
        invg[j][3] = __builtin_amdgcn_rcpf(gv.w);
        b2v[j][0] = bv.x; b2v[j][1] = bv.y; b2v[j][2] = bv.z; b2v[j][3] = bv.w;
    }
    #pragma unroll
    for (int i = 0; i < 4; ++i) {
        int row = 16 * i + l16;
        if (row < NN) {
            int gtok = win2tok(win * NN + row);
            float mean = MRm[row];
            float sd = MRs[row];
            #pragma unroll
            for (int j = 0; j < 2; ++j) {
                float4 bb = *(const float4*)&bias2[wn + 16 * j + quad * 4];
                ushort4 hv = *(const ushort4*)&AH[row * 136 + wn + 16 * j + quad * 4];
                float4 cur;
                cur.x = (bf2f(hv.x) - b2v[j][0]) * (invg[j][0] * sd) + mean + acc2[j][i][0] + bb.x;
                cur.y = (bf2f(hv.y) - b2v[j][1]) * (invg[j][1] * sd) + mean + acc2[j][i][1] + bb.y;
                cur.z = (bf2f(hv.z) - b2v[j][2]) * (invg[j][2] * sd) + mean + acc2[j][i][2] + bb.z;
                cur.w = (bf2f(hv.w) - b2v[j][3]) * (invg[j][3] * sd) + mean + acc2[j][i][3] + bb.w;
                *(float4*)(out + (size_t)gtok * CC + wn + 16 * j + quad * 4) = cur;
            }
        }
    }
}

// ============ launch ============
extern "C" void kernel_launch(void* const* d_in, const int* in_sizes, int n_in,
                              void* d_out, int out_size, void* d_ws, size_t ws_size,
                              hipStream_t stream) {
    const float* x       = (const float*)d_in[0];
    const float* norm1_g = (const float*)d_in[1];
    const float* norm1_b = (const float*)d_in[2];
    const float* qkv_w   = (const float*)d_in[3];
    const float* qkv_b   = (const float*)d_in[4];
    const float* rpb     = (const float*)d_in[5];
    const float* proj_w  = (const float*)d_in[6];
    const float* proj_b  = (const float*)d_in[7];
    const float* norm2_g = (const float*)d_in[8];
    const float* norm2_b = (const float*)d_in[9];
    const float* fc1_w   = (const float*)d_in[10];
    const float* fc1_b   = (const float*)d_in[11];
    const float* fc2_w   = (const float*)d_in[12];
    const float* fc2_b   = (const float*)d_in[13];
    const int*   rel_idx = (const int*)d_in[14];

    char* ws = (char*)d_ws;
    float*    biasT = (float*)ws;
    ushort_t* wall  = (ushort_t*)(ws + 65536);
    ushort_t* wqkv  = wall;
    ushort_t* wproj = wall + 49152;
    ushort_t* wfc1  = wall + 65536;
    ushort_t* wfc2  = wall + 131072;

    prep_all<<<dim3(772), dim3(256), 0, stream>>>(
        qkv_w, proj_w, fc1_w, fc2_w, wall, rpb, rel_idx, biasT);
    swin_fused<<<dim3(NWIN), dim3(256), 0, stream>>>(
        x, norm1_g, norm1_b, wqkv, qkv_b, biasT,
        wproj, proj_b, norm2_g, norm2_b,
        wfc1, fc1_b, wfc2, fc2_b, (float*)d_out);
}

// Round 16
// 271.351 us; speedup vs baseline: 1.2703x; 1.2651x over previous
//
#include <hip/hip_runtime.h>

typedef unsigned short ushort_t;
typedef unsigned int uint_t;

typedef __bf16 bf16x8 __attribute__((ext_vector_type(8)));
typedef float f32x4 __attribute__((ext_vector_type(4)));

static __device__ __forceinline__ float bf2f(ushort_t h) {
    return __uint_as_float(((uint_t)h) << 16);
}
static __device__ __forceinline__ ushort_t f2bf(float f) {
    uint_t u = __float_as_uint(f);
    u = u + 0x7FFFu + ((u >> 16) & 1u);
    return (ushort_t)(u >> 16);
}
// pack two floats as bf16 (round-half-up) into one dword: low=lo, high=hi
static __device__ __forceinline__ uint_t pkbf(float lo, float hi) {
    uint_t a = __float_as_uint(lo) + 0x8000u;
    uint_t b = __float_as_uint(hi) + 0x8000u;
    return __builtin_amdgcn_perm(b, a, 0x07060302u);
}

// ---------------- constants ----------------
#define BB 32
#define HH 56
#define WW_ 56
#define CC 128
#define NHEAD 4
#define WS 7
#define SS 3
#define LL (HH * WW_)           // 3136
#define NTOK (BB * LL)          // 100352
#define NWIN (BB * 64)          // 2048
#define NN 49
#define HD 32
#define PLS 40                  // P half LDS stride (shorts) — conflict-free
#define VTS 72                  // Vt LDS stride (shorts) — conflict-free

// windowed token -> global token (shift map)
static __device__ __forceinline__ int win2tok(int wid) {
    int win = wid / NN, t = wid - win * NN;
    int bb = win >> 6, wrem = win & 63;
    int wi = wrem >> 3, wj = wrem & 7;
    int ti = t / WS, tj = t - ti * WS;
    int hh = wi * WS + ti + SS; if (hh >= HH) hh -= HH;
    int ww = wj * WS + tj + SS; if (ww >= WW_) ww -= WW_;
    return bb * LL + hh * WW_ + ww;
}

// ============ merged prep: weights fp32->bf16 (blocks 0..767) +
//              bias table x log2(e) (blocks 768..771) ============
// bias scaled by log2e so softmax uses raw v_exp (2^x) — r13.
__global__ __launch_bounds__(256) void prep_all(
    const float* __restrict__ qkv_w, const float* __restrict__ proj_w,
    const float* __restrict__ fc1_w, const float* __restrict__ fc2_w,
    ushort_t* __restrict__ dst,
    const float* __restrict__ rpb, const int* __restrict__ rel_idx,
    float* __restrict__ bias) {
    int b = blockIdx.x;
    if (b < 768) {
        int i = b * 256 + threadIdx.x;   // 0 .. 196607
        const float* src;
        int off;
        if (i < 49152)        { src = qkv_w;  off = i; }
        else if (i < 65536)   { src = proj_w; off = i - 49152; }
        else if (i < 131072)  { src = fc1_w;  off = i - 65536; }
        else                  { src = fc2_w;  off = i - 131072; }
        dst[i] = f2bf(src[off]);
    } else {
        int h = b - 768;
        for (int idx = threadIdx.x; idx < 4096; idx += 256) {
            int i = idx >> 6, j = idx & 63;
            float v = 0.f;
            if (i < NN && j < NN)
                v = rpb[(size_t)rel_idx[i * NN + j] * NHEAD + h] * 1.4426950409f;
            bias[h * 4096 + idx] = v;
        }
    }
}

// ============ fully-fused: LN1+QKV+attn+proj+residual+LN2+MLP ============
// r16 = EXACT r13 checkpoint (verified best: kernel 176.6 us, VGPR 124,
// occ 21.6%, total 271.8 us). r14 (vx prefetch) and r15 (pkbf pair-pack)
// both tipped the allocator past the 128-VGPR cliff (140 VGPR, occ 11.7%,
// +70-107 us) — the kernel has ZERO register headroom; grafts worth <=5 us
// risk 60+ us. Locking in the proven optimum.
// Base: r10 structure (QK swizzle, Vt in LDS, 3 blocks/CU) + r13 exp2
// foldings (softmax scale/bias pre-scaled by log2e; gelu constants folded).
__global__ __launch_bounds__(256) void swin_fused(
    const float* __restrict__ x, const float* __restrict__ g1,
    const float* __restrict__ b1ln, const ushort_t* __restrict__ wq,
    const float* __restrict__ qkv_b, const float* __restrict__ bias,
    const ushort_t* __restrict__ wp, const float* __restrict__ proj_b,
    const float* __restrict__ g2, const float* __restrict__ b2,
    const ushort_t* __restrict__ w1, const float* __restrict__ fc1b,
    const ushort_t* __restrict__ w2, const float* __restrict__ bias2,
    float* __restrict__ out) {
    __shared__ __align__(16) ushort_t U[16384];
    __shared__ __align__(16) ushort_t HV[NHEAD][32 * VTS];
    __shared__ float MRm[64];
    __shared__ float MRs[64];
    const int tid = threadIdx.x;
    const int wave = tid >> 6;
    const int lane = tid & 63;
    const int l16 = lane & 15;
    const int quad = lane >> 4;
    const int h = wave;
    const int win = blockIdx.x;
    const int wn = wave * 32;
    const float scale = 0.25503492f;   // 32^-0.5 * log2(e)

    ushort_t* XLN = U;                         // 64 x 136
    char* QK = (char*)(U + h * 4096);          // 64 rows x 128 B, swizzled
    ushort_t* PL = U + h * 4096;               // 64 x 40 (overlays QK, own wave)
    ushort_t* VT = HV[h];
    ushort_t* AH = U;                          // MLP phase: 64 x 136
    ushort_t* PS = (ushort_t*)HV;              // MLP phase: 64 x 136 (8704<=9216)

    // ---- LN1 (4 threads per row, rows >=49 clamped to token 0) ----
    {
        int row = tid >> 2;
        int ch0 = (tid & 3) * 32;
        int t = (row < NN) ? row : 0;
        int gtok = win2tok(win * NN + t);
        const float* xp = x + (size_t)gtok * CC + ch0;
        float v[32];
        float s = 0.f, sq = 0.f;
        #pragma unroll
        for (int i = 0; i < 4; ++i) {
            float4 a0 = *(const float4*)(xp + i * 8);
            float4 a1 = *(const float4*)(xp + i * 8 + 4);
            v[i * 8 + 0] = a0.x; v[i * 8 + 1] = a0.y;
            v[i * 8 + 2] = a0.z; v[i * 8 + 3] = a0.w;
            v[i * 8 + 4] = a1.x; v[i * 8 + 5] = a1.y;
            v[i * 8 + 6] = a1.z; v[i * 8 + 7] = a1.w;
            #pragma unroll
            for (int j = 0; j < 8; ++j) { s += v[i * 8 + j]; sq += v[i * 8 + j] * v[i * 8 + j]; }
        }
        s += __shfl_xor(s, 1);  sq += __shfl_xor(sq, 1);
        s += __shfl_xor(s, 2);  sq += __shfl_xor(sq, 2);
        float mean = s * (1.0f / 128.0f);
        float var = sq * (1.0f / 128.0f) - mean * mean;
        float rstd = rsqrtf(var + 1e-5f);
        #pragma unroll
        for (int i = 0; i < 4; ++i) {
            ushort_t tmp[8];
            #pragma unroll
            for (int j = 0; j < 8; ++j) {
                int c = ch0 + i * 8 + j;
                tmp[j] = f2bf((v[i * 8 + j] - mean) * rstd * g1[c] + b1ln[c]);
            }
            *(uint4*)&XLN[row * 136 + ch0 + i * 8] = *(const uint4*)tmp;
        }
    }
    __syncthreads();   // XLN ready

    // ---- cache token frags in regs ----
    bf16x8 tf[4][4];
    #pragma unroll
    for (int kk = 0; kk < 4; ++kk)
        #pragma unroll
        for (int i = 0; i < 4; ++i)
            tf[kk][i] = *(const bf16x8*)&XLN[(16 * i + l16) * 136 + kk * 32 + quad * 8];
    __syncthreads();   // XLN dead; U becomes QK region

    // ---- Q (swapped: D^T[qcol][token]), scale(+log2e) folded; j-outer ----
    #pragma unroll
    for (int j = 0; j < 2; ++j) {
        f32x4 s1[4];
        #pragma unroll
        for (int i = 0; i < 4; ++i)
            s1[i] = (f32x4){0.f, 0.f, 0.f, 0.f};
        #pragma unroll
        for (int kk = 0; kk < 4; ++kk) {
            bf16x8 wf = *(const bf16x8*)&wq[(size_t)(h * 32 + 16 * j + l16) * 128 + kk * 32 + quad * 8];
            #pragma unroll
            for (int i = 0; i < 4; ++i)
                s1[i] = __builtin_amdgcn_mfma_f32_16x16x32_bf16(wf, tf[kk][i], s1[i], 0, 0, 0);
        }
        float4 bv = *(const float4*)&qkv_b[h * 32 + 16 * j + quad * 4];
        #pragma unroll
        for (int i = 0; i < 4; ++i) {
            uint2 pk;
            pk.x = pkbf((s1[i][0] + bv.x) * scale, (s1[i][1] + bv.y) * scale);
            pk.y = pkbf((s1[i][2] + bv.z) * scale, (s1[i][3] + bv.w) * scale);
            int row = 16 * i + l16;
            *(uint2*)(QK + row * 128 + ((32 * j + 8 * quad) ^ ((row & 7) << 4))) = pk;
        }
    }
    // ---- K (swapped); j-outer ----
    #pragma unroll
    for (int j = 0; j < 2; ++j) {
        f32x4 s1[4];
        #pragma unroll
        for (int i = 0; i < 4; ++i)
            s1[i] = (f32x4){0.f, 0.f, 0.f, 0.f};
        #pragma unroll
        for (int kk = 0; kk < 4; ++kk) {
            bf16x8 wf = *(const bf16x8*)&wq[(size_t)(128 + h * 32 + 16 * j + l16) * 128 + kk * 32 + quad * 8];
            #pragma unroll
            for (int i = 0; i < 4; ++i)
                s1[i] = __builtin_amdgcn_mfma_f32_16x16x32_bf16(wf, tf[kk][i], s1[i], 0, 0, 0);
        }
        float4 bv = *(const float4*)&qkv_b[128 + h * 32 + 16 * j + quad * 4];
        #pragma unroll
        for (int i = 0; i < 4; ++i) {
            uint2 pk;
            pk.x = pkbf(s1[i][0] + bv.x, s1[i][1] + bv.y);
            pk.y = pkbf(s1[i][2] + bv.z, s1[i][3] + bv.w);
            int row = 16 * i + l16;
            *(uint2*)(QK + row * 128 + ((64 + 32 * j + 8 * quad) ^ ((row & 7) << 4))) = pk;
        }
    }
    // ---- V (non-swapped: D[token][vcol] -> Vt[d][token]); j-outer ----
    #pragma unroll
    for (int j = 0; j < 2; ++j) {
        f32x4 sv[4];
        #pragma unroll
        for (int i = 0; i < 4; ++i)
            sv[i] = (f32x4){0.f, 0.f, 0.f, 0.f};
        #pragma unroll
        for (int kk = 0; kk < 4; ++kk) {
            bf16x8 wf = *(const bf16x8*)&wq[(size_t)(256 + h * 32 + 16 * j + l16) * 128 + kk * 32 + quad * 8];
            #pragma unroll
            for (int i = 0; i < 4; ++i)
                sv[i] = __builtin_amdgcn_mfma_f32_16x16x32_bf16(tf[kk][i], wf, sv[i], 0, 0, 0);
        }
        float bvv = qkv_b[256 + h * 32 + 16 * j + l16];
        #pragma unroll
        for (int i = 0; i < 4; ++i) {
            uint2 pk;
            pk.x = pkbf(sv[i][0] + bvv, sv[i][1] + bvv);
            pk.y = pkbf(sv[i][2] + bvv, sv[i][3] + bvv);
            *(uint2*)&VT[(16 * j + l16) * VTS + 16 * i + quad * 4] = pk;
        }
    }

    // ---- S = QK^T (K dim = HD = 32 exactly) ----
    f32x4 s[4][4];
    {
        bf16x8 qa[4], kb[4];
        #pragma unroll
        for (int t = 0; t < 4; ++t) {
            int row = 16 * t + l16;
            int swz = (row & 7) << 4;
            qa[t] = *(const bf16x8*)(QK + row * 128 + ((16 * quad) ^ swz));
            kb[t] = *(const bf16x8*)(QK + row * 128 + ((64 + 16 * quad) ^ swz));
        }
        #pragma unroll
        for (int mi = 0; mi < 4; ++mi)
            #pragma unroll
            for (int ni = 0; ni < 4; ++ni) {
                f32x4 z = {0.f, 0.f, 0.f, 0.f};
                s[mi][ni] = __builtin_amdgcn_mfma_f32_16x16x32_bf16(qa[mi], kb[ni], z, 0, 0, 0);
            }
    }

    // ---- + relative-position bias (pre-scaled by log2e in prep_all) ----
    const float* bh = bias + h * 4096;
    #pragma unroll
    for (int mi = 0; mi < 4; ++mi)
        #pragma unroll
        for (int ni = 0; ni < 4; ++ni)
            #pragma unroll
            for (int r = 0; r < 4; ++r)
                s[mi][ni][r] += bh[(16 * mi + quad * 4 + r) * 64 + 16 * ni + l16];

    // ---- softmax over cols: exp(x) computed as 2^(x*log2e) with log2e
    //      already folded into scale+bias -> raw v_exp. (no max-sub:
    //      |scores| << 2, shift-invariant, r5-verified; cols >=49 masked) ----
    #pragma unroll
    for (int mi = 0; mi < 4; ++mi)
        #pragma unroll
        for (int r = 0; r < 4; ++r) {
            float e0 = __builtin_amdgcn_exp2f(s[mi][0][r]);
            float e1 = __builtin_amdgcn_exp2f(s[mi][1][r]);
            float e2 = __builtin_amdgcn_exp2f(s[mi][2][r]);
            float e3 = (l16 == 0) ? __builtin_amdgcn_exp2f(s[mi][3][r]) : 0.f;
            float sum = (e0 + e1) + (e2 + e3);
            sum += __shfl_xor(sum, 1);
            sum += __shfl_xor(sum, 2);
            sum += __shfl_xor(sum, 4);
            sum += __shfl_xor(sum, 8);
            float inv = __builtin_amdgcn_rcpf(sum);
            s[mi][0][r] = e0 * inv;
            s[mi][1][r] = e1 * inv;
            s[mi][2][r] = e2 * inv;
            s[mi][3][r] = e3 * inv;
        }

    // ---- pack P to bf16 regs (frees f32 S before PV) ----
    uint2 pP[4][4];
    #pragma unroll
    for (int mi = 0; mi < 4; ++mi)
        #pragma unroll
        for (int ni = 0; ni < 4; ++ni) {
            pP[mi][ni].x = pkbf(s[mi][ni][0], s[mi][ni][1]);
            pP[mi][ni].y = pkbf(s[mi][ni][2], s[mi][ni][3]);
        }

    // ---- O^T = Vt · P^T, P streamed in two 32-col halves through PL ----
    f32x4 o[2][4];
    #pragma unroll
    for (int k0 = 0; k0 < 64; k0 += 32) {
        int nb = k0 >> 4;
        #pragma unroll
        for (int mi = 0; mi < 4; ++mi)
            #pragma unroll
            for (int nn = 0; nn < 2; ++nn) {
                uint2 pk = pP[mi][nb + nn];
                int base = (16 * mi + quad * 4) * PLS + 16 * nn + l16;
                PL[base] = (ushort_t)pk.x;
                PL[base + PLS] = (ushort_t)(pk.x >> 16);
                PL[base + 2 * PLS] = (ushort_t)pk.y;
                PL[base + 3 * PLS] = (ushort_t)(pk.y >> 16);
            }
        bf16x8 va[2], pb[4];
        #pragma unroll
        for (int it = 0; it < 2; ++it)
            va[it] = *(const bf16x8*)&VT[(16 * it + l16) * VTS + k0 + quad * 8];
        #pragma unroll
        for (int jt = 0; jt < 4; ++jt)
            pb[jt] = *(const bf16x8*)&PL[(16 * jt + l16) * PLS + quad * 8];
        #pragma unroll
        for (int it = 0; it < 2; ++it)
            #pragma unroll
            for (int jt = 0; jt < 4; ++jt) {
                if (k0 == 0) {
                    f32x4 z = {0.f, 0.f, 0.f, 0.f};
                    o[it][jt] = __builtin_amdgcn_mfma_f32_16x16x32_bf16(va[it], pb[jt], z, 0, 0, 0);
                } else {
                    o[it][jt] = __builtin_amdgcn_mfma_f32_16x16x32_bf16(va[it], pb[jt], o[it][jt], 0, 0, 0);
                }
            }
    }
    __syncthreads();   // all waves done reading QK/PL/VT

    // ---- O -> AH (LDS, all 64 rows; pads are finite token-0 clones) ----
    #pragma unroll
    for (int jt = 0; jt < 4; ++jt) {
        int m = 16 * jt + l16;
        #pragma unroll
        for (int it = 0; it < 2; ++it) {
            ushort4 st;
            st.x = f2bf(o[it][jt][0]);
            st.y = f2bf(o[it][jt][1]);
            st.z = f2bf(o[it][jt][2]);
            st.w = f2bf(o[it][jt][3]);
            *(ushort4*)&AH[m * 136 + h * HD + 16 * it + quad * 4] = st;
        }
    }
    __syncthreads();   // AH (attn result, 64x128) ready

    // ---- proj: AH -> PS (bf16 64x136) ----
    {
        f32x4 pa[2][4];
        #pragma unroll
        for (int j = 0; j < 2; ++j)
            #pragma unroll
            for (int i = 0; i < 4; ++i)
                pa[j][i] = (f32x4){0.f, 0.f, 0.f, 0.f};
        #pragma unroll
        for (int kk = 0; kk < 4; ++kk) {
            bf16x8 af[4];
            #pragma unroll
            for (int i = 0; i < 4; ++i)
                af[i] = *(const bf16x8*)&AH[(16 * i + l16) * 136 + kk * 32 + quad * 8];
            #pragma unroll
            for (int j = 0; j < 2; ++j) {
                bf16x8 wf = *(const bf16x8*)&wp[(size_t)(wn + 16 * j + l16) * 128 + kk * 32 + quad * 8];
                #pragma unroll
                for (int i = 0; i < 4; ++i)
                    pa[j][i] = __builtin_amdgcn_mfma_f32_16x16x32_bf16(wf, af[i], pa[j][i], 0, 0, 0);
            }
        }
        #pragma unroll
        for (int j = 0; j < 2; ++j) {
            float4 bv = *(const float4*)&proj_b[wn + 16 * j + quad * 4];
            #pragma unroll
            for (int i = 0; i < 4; ++i) {
                uint2 pk;
                pk.x = pkbf(pa[j][i][0] + bv.x, pa[j][i][1] + bv.y);
                pk.y = pkbf(pa[j][i][2] + bv.z, pa[j][i][3] + bv.w);
                *(uint2*)&PS[(16 * i + l16) * 136 + wn + 16 * j + quad * 4] = pk;
            }
        }
    }
    __syncthreads();   // PS (proj result) ready; AH free for h2

    // ---- residual + LN2: h2 -> AH (bf16), (mean, sd) -> MR ----
    {
        int row = tid >> 2;
        int ch0 = (tid & 3) * 32;
        int t = (row < NN) ? row : 0;
        int gtok = win2tok(win * NN + t);
        const float* xp = x + (size_t)gtok * CC + ch0;
        float v[32];
        float s2 = 0.f, sq = 0.f;
        #pragma unroll
        for (int i = 0; i < 4; ++i) {
            float4 a0 = *(const float4*)(xp + i * 8);
            float4 a1 = *(const float4*)(xp + i * 8 + 4);
            ushort4 p0 = *(const ushort4*)&PS[row * 136 + ch0 + i * 8];
            ushort4 p1 = *(const ushort4*)&PS[row * 136 + ch0 + i * 8 + 4];
            v[i * 8 + 0] = a0.x + bf2f(p0.x); v[i * 8 + 1] = a0.y + bf2f(p0.y);
            v[i * 8 + 2] = a0.z + bf2f(p0.z); v[i * 8 + 3] = a0.w + bf2f(p0.w);
            v[i * 8 + 4] = a1.x + bf2f(p1.x); v[i * 8 + 5] = a1.y + bf2f(p1.y);
            v[i * 8 + 6] = a1.z + bf2f(p1.z); v[i * 8 + 7] = a1.w + bf2f(p1.w);
            #pragma unroll
            for (int j = 0; j < 8; ++j) { s2 += v[i * 8 + j]; sq += v[i * 8 + j] * v[i * 8 + j]; }
        }
        s2 += __shfl_xor(s2, 1);  sq += __shfl_xor(sq, 1);
        s2 += __shfl_xor(s2, 2);  sq += __shfl_xor(sq, 2);
        float mean = s2 * (1.0f / 128.0f);
        float var = sq * (1.0f / 128.0f) - mean * mean;
        float rstd = rsqrtf(var + 1e-5f);
        if ((tid & 3) == 0) {
            MRm[row] = mean;
            MRs[row] = (var + 1e-5f) * rstd;   // = sqrt(var+eps) = 1/rstd
        }
        #pragma unroll
        for (int i = 0; i < 4; ++i) {
            ushort_t tmp[8];
            #pragma unroll
            for (int j = 0; j < 8; ++j) {
                int c = ch0 + i * 8 + j;
                tmp[j] = f2bf((v[i * 8 + j] - mean) * rstd * g2[c] + b2[c]);
            }
            *(uint4*)&AH[row * 136 + ch0 + i * 8] = *(const uint4*)tmp;
        }
    }
    __syncthreads();   // AH = h2 ready; PS consumed

    // ---- MLP c-loop ----
    f32x4 acc2[2][4];
    #pragma unroll
    for (int j = 0; j < 2; ++j)
        #pragma unroll
        for (int i = 0; i < 4; ++i)
            acc2[j][i] = (f32x4){0.f, 0.f, 0.f, 0.f};

    for (int c = 0; c < 4; ++c) {
        f32x4 s1[2][4];
        #pragma unroll
        for (int j = 0; j < 2; ++j)
            #pragma unroll
            for (int i = 0; i < 4; ++i)
                s1[j][i] = (f32x4){0.f, 0.f, 0.f, 0.f};
        #pragma unroll
        for (int kk = 0; kk < 4; ++kk) {
            bf16x8 hf[4];
            #pragma unroll
            for (int i = 0; i < 4; ++i)
                hf[i] = *(const bf16x8*)&AH[(16 * i + l16) * 136 + kk * 32 + quad * 8];
            #pragma unroll
            for (int j = 0; j < 2; ++j) {
                bf16x8 wf = *(const bf16x8*)&w1[(size_t)(c * 128 + wn + 16 * j + l16) * 128 + kk * 32 + quad * 8];
                #pragma unroll
                for (int i = 0; i < 4; ++i)
                    s1[j][i] = __builtin_amdgcn_mfma_f32_16x16x32_bf16(wf, hf[i], s1[j][i], 0, 0, 0);
            }
        }
        uint2 pk[2][4];
        #pragma unroll
        for (int j = 0; j < 2; ++j) {
            float4 bv = *(const float4*)&fc1b[c * 128 + wn + 16 * j + quad * 4];
            #pragma unroll
            for (int i = 0; i < 4; ++i) {
                float g[4];
                #pragma unroll
                for (int r = 0; r < 4; ++r) {
                    float u = s1[j][i][r] + ((const float*)&bv)[r];
                    float u2 = u * u;
                    // z2 = z*log2e: gelu sigmoid exp via raw v_exp (2^x)
                    float z2 = u * __builtin_fmaf(0.10294324f, u2, 2.3022084f);
                    float e = __builtin_amdgcn_exp2f(-z2);
                    g[r] = u * __builtin_amdgcn_rcpf(1.0f + e);
                }
                pk[j][i].x = pkbf(g[0], g[1]);
                pk[j][i].y = pkbf(g[2], g[3]);
            }
        }
        __syncthreads();
        #pragma unroll
        for (int j = 0; j < 2; ++j)
            #pragma unroll
            for (int i = 0; i < 4; ++i)
                *(uint2*)&PS[(16 * i + l16) * 136 + wn + 16 * j + quad * 4] = pk[j][i];
        __syncthreads();
        #pragma unroll
        for (int kk = 0; kk < 4; ++kk) {
            bf16x8 pf[4];
            #pragma unroll
            for (int i = 0; i < 4; ++i)
                pf[i] = *(const bf16x8*)&PS[(16 * i + l16) * 136 + kk * 32 + quad * 8];
            #pragma unroll
            for (int j = 0; j < 2; ++j) {
                bf16x8 wf = *(const bf16x8*)&w2[(size_t)(wn + 16 * j + l16) * 512 + c * 128 + kk * 32 + quad * 8];
                #pragma unroll
                for (int i = 0; i < 4; ++i)
                    acc2[j][i] = __builtin_amdgcn_mfma_f32_16x16x32_bf16(wf, pf[i], acc2[j][i], 0, 0, 0);
            }
        }
    }

    // ---- epilogue: x2 = (h2 - b2)*sd/g2 + mean; out = x2 + mlp + bias2 ----
    float invg[2][4], b2v[2][4];
    #pragma unroll
    for (int j = 0; j < 2; ++j) {
        float4 gv = *(const float4*)&g2[wn + 16 * j + quad * 4];
        float4 bv = *(const float4*)&b2[wn + 16 * j + quad * 4];
        invg[j][0] = __builtin_amdgcn_rcpf(gv.x);
        invg[j][1] = __builtin_amdgcn_rcpf(gv.y);
        invg[j][2] = __builtin_amdgcn_rcpf(gv.z);
        invg[j][3] = __builtin_amdgcn_rcpf(gv.w);
        b2v[j][0] = bv.x; b2v[j][1] = bv.y; b2v[j][2] = bv.z; b2v[j][3] = bv.w;
    }
    #pragma unroll
    for (int i = 0; i < 4; ++i) {
        int row = 16 * i + l16;
        if (row < NN) {
            int gtok = win2tok(win * NN + row);
            float mean = MRm[row];
            float sd = MRs[row];
            #pragma unroll
            for (int j = 0; j < 2; ++j) {
                float4 bb = *(const float4*)&bias2[wn + 16 * j + quad * 4];
                ushort4 hv = *(const ushort4*)&AH[row * 136 + wn + 16 * j + quad * 4];
                float4 cur;
                cur.x = (bf2f(hv.x) - b2v[j][0]) * (invg[j][0] * sd) + mean + acc2[j][i][0] + bb.x;
                cur.y = (bf2f(hv.y) - b2v[j][1]) * (invg[j][1] * sd) + mean + acc2[j][i][1] + bb.y;
                cur.z = (bf2f(hv.z) - b2v[j][2]) * (invg[j][2] * sd) + mean + acc2[j][i][2] + bb.z;
                cur.w = (bf2f(hv.w) - b2v[j][3]) * (invg[j][3] * sd) + mean + acc2[j][i][3] + bb.w;
                *(float4*)(out + (size_t)gtok * CC + wn + 16 * j + quad * 4) = cur;
            }
        }
    }
}

// ============ launch ============
extern "C" void kernel_launch(void* const* d_in, const int* in_sizes, int n_in,
                              void* d_out, int out_size, void* d_ws, size_t ws_size,
                              hipStream_t stream) {
    const float* x       = (const float*)d_in[0];
    const float* norm1_g = (const float*)d_in[1];
    const float* norm1_b = (const float*)d_in[2];
    const float* qkv_w   = (const float*)d_in[3];
    const float* qkv_b   = (const float*)d_in[4];
    const float* rpb     = (const float*)d_in[5];
    const float* proj_w  = (const float*)d_in[6];
    const float* proj_b  = (const float*)d_in[7];
    const float* norm2_g = (const float*)d_in[8];
    const float* norm2_b = (const float*)d_in[9];
    const float* fc1_w   = (const float*)d_in[10];
    const float* fc1_b   = (const float*)d_in[11];
    const float* fc2_w   = (const float*)d_in[12];
    const float* fc2_b   = (const float*)d_in[13];
    const int*   rel_idx = (const int*)d_in[14];

    char* ws = (char*)d_ws;
    float*    biasT = (float*)ws;
    ushort_t* wall  = (ushort_t*)(ws + 65536);
    ushort_t* wqkv  = wall;
    ushort_t* wproj = wall + 49152;
    ushort_t* wfc1  = wall + 65536;
    ushort_t* wfc2  = wall + 131072;

    prep_all<<<dim3(772), dim3(256), 0, stream>>>(
        qkv_w, proj_w, fc1_w, fc2_w, wall, rpb, rel_idx, biasT);
    swin_fused<<<dim3(NWIN), dim3(256), 0, stream>>>(
        x, norm1_g, norm1_b, wqkv, qkv_b, biasT,
        wproj, proj_b, norm2_g, norm2_b,
        wfc1, fc1_b, wfc2, fc2_b, (float*)d_out);
}